// Round 1
// baseline (222708.130 us; speedup 1.0000x reference)
//
#include <hip/hip_runtime.h>
#include <hip/hip_cooperative_groups.h>

namespace cg = cooperative_groups;

// Problem sizes (fixed by the reference)
constexpr int D_  = 1024;   // input/hidden size
constexpr int E_  = 2048;   // expanded size
constexpr int B_  = 16;     // batch
constexpr int T_  = 1024;   // time steps

constexpr int NWG = 256;    // one workgroup per CU
constexpr int TPB = 256;    // 4 waves
constexpr int R1  = E_ / NWG;  // 8 rows of W1 per WG
constexpr int R2  = D_ / NWG;  // 4 rows of W2/Wgx/Wgh per WG

// LDS row strides, padded by 4 floats to break power-of-2 bank aliasing
constexpr int S1 = 2052;    // for 2048-wide rows (W1, W2)
constexpr int SG = 1028;    // for 1024-wide rows (Wgx, Wgh)

constexpr int LDS_FLOATS = R1 * S1 + R2 * S1 + 2 * R2 * SG + TPB;
constexpr int LDS_BYTES  = LDS_FLOATS * 4;  // 132,416 B <= 160 KB/CU

__global__ void __launch_bounds__(TPB, 1)
elman_persistent(const float* __restrict__ x, const float* __restrict__ h0,
                 const float* __restrict__ W1, const float* __restrict__ W2,
                 const float* __restrict__ Wgx, const float* __restrict__ Wgh,
                 const float* __restrict__ bias,
                 float* __restrict__ out, float* __restrict__ ws)
{
    extern __shared__ float lds[];
    float* w1s  = lds;                 // [R1][S1]
    float* w2s  = w1s  + R1 * S1;      // [R2][S1]
    float* wgxs = w2s  + R2 * S1;      // [R2][SG]
    float* wghs = wgxs + R2 * SG;      // [R2][SG]
    float* red  = wghs + R2 * SG;      // [TPB]

    float* hidden = ws;                // [B][E] b-major
    float* hnew   = ws + B_ * E_;      // [B][D] b-major

    const int g   = blockIdx.x;
    const int tid = threadIdx.x;

    // ---- one-time: stage this WG's weight slices into LDS (float4) ----
    for (int i = tid; i < R1 * (E_ / 4); i += TPB) {
        int r = i >> 9, c = (i & 511) * 4;
        *(float4*)(w1s + r * S1 + c) =
            *(const float4*)(W1 + (size_t)(g * R1 + r) * (2 * D_) + c);
    }
    for (int i = tid; i < R2 * (E_ / 4); i += TPB) {
        int r = i >> 9, c = (i & 511) * 4;
        *(float4*)(w2s + r * S1 + c) =
            *(const float4*)(W2 + (size_t)(g * R2 + r) * E_ + c);
    }
    for (int i = tid; i < R2 * (D_ / 4); i += TPB) {
        int r = i >> 8, c = (i & 255) * 4;
        *(float4*)(wgxs + r * SG + c) =
            *(const float4*)(Wgx + (size_t)(g * R2 + r) * D_ + c);
        *(float4*)(wghs + r * SG + c) =
            *(const float4*)(Wgh + (size_t)(g * R2 + r) * D_ + c);
    }
    __syncthreads();

    const int b   = tid & 15;          // batch lane
    const int rr1 = (tid >> 4) & 7;    // P1 row within slice
    const int ks1 = tid >> 7;          // P1 K-half: 0 -> x part, 1 -> h part
    const int rr2 = (tid >> 4) & 3;    // P2/P3 row within slice
    const int ks2 = tid >> 6;          // P2/P3 K-quarter 0..3

    cg::grid_group grid = cg::this_grid();

    for (int t = 0; t < T_; ++t) {
        const float* xt = x + (size_t)t * B_ * D_;
        const float* h  = (t == 0) ? h0 : (out + (size_t)(t - 1) * B_ * D_);

        // ---- P1: hidden = tanh(W1 @ [x_t; h]) ----
        {
            const float* act  = ((ks1 == 0) ? xt : h) + b * D_;
            const float* wrow = w1s + rr1 * S1 + ks1 * D_;
            float ax = 0.f, ay = 0.f, az = 0.f, aw = 0.f;
            for (int k = 0; k < D_; k += 4) {
                float4 a = *(const float4*)(act + k);
                float4 w = *(const float4*)(wrow + k);
                ax = fmaf(a.x, w.x, ax); ay = fmaf(a.y, w.y, ay);
                az = fmaf(a.z, w.z, az); aw = fmaf(a.w, w.w, aw);
            }
            red[tid] = (ax + ay) + (az + aw);
            __syncthreads();
            if (tid < 128) {
                float v = tanhf(red[tid] + red[tid + 128]);
                hidden[b * E_ + (g * R1 + rr1)] = v;
            }
        }
        __threadfence();
        grid.sync();

        // ---- P2: hnew = W2 @ hidden ----
        {
            const float* act  = hidden + b * E_ + ks2 * 512;
            const float* wrow = w2s + rr2 * S1 + ks2 * 512;
            float ax = 0.f, ay = 0.f, az = 0.f, aw = 0.f;
            for (int k = 0; k < 512; k += 4) {
                float4 a = *(const float4*)(act + k);
                float4 w = *(const float4*)(wrow + k);
                ax = fmaf(a.x, w.x, ax); ay = fmaf(a.y, w.y, ay);
                az = fmaf(a.z, w.z, az); aw = fmaf(a.w, w.w, aw);
            }
            red[tid] = (ax + ay) + (az + aw);
            __syncthreads();
            if (tid < 64) {
                float v = red[tid] + red[tid + 64] + red[tid + 128] + red[tid + 192];
                hnew[b * D_ + (g * R2 + rr2)] = v;
            }
        }
        __threadfence();
        grid.sync();

        // ---- P3: out = hnew * silu(Wgx@x_t + Wgh@hnew + bias) ----
        {
            const float* act  = (ks2 < 2) ? (xt + b * D_ + ks2 * 512)
                                          : (hnew + b * D_ + (ks2 - 2) * 512);
            const float* wrow = (ks2 < 2) ? (wgxs + rr2 * SG + ks2 * 512)
                                          : (wghs + rr2 * SG + (ks2 - 2) * 512);
            float ax = 0.f, ay = 0.f, az = 0.f, aw = 0.f;
            for (int k = 0; k < 512; k += 4) {
                float4 a = *(const float4*)(act + k);
                float4 w = *(const float4*)(wrow + k);
                ax = fmaf(a.x, w.x, ax); ay = fmaf(a.y, w.y, ay);
                az = fmaf(a.z, w.z, az); aw = fmaf(a.w, w.w, aw);
            }
            red[tid] = (ax + ay) + (az + aw);
            __syncthreads();
            if (tid < 64) {
                int row = g * R2 + rr2;
                float u = red[tid] + red[tid + 64] + red[tid + 128] + red[tid + 192]
                          + bias[row];
                float hn  = hnew[b * D_ + row];
                float sig = 1.0f / (1.0f + __expf(-u));
                out[(size_t)t * B_ * D_ + b * D_ + row] = hn * (u * sig);
            }
        }
        __threadfence();
        grid.sync();
    }
}

extern "C" void kernel_launch(void* const* d_in, const int* in_sizes, int n_in,
                              void* d_out, int out_size, void* d_ws, size_t ws_size,
                              hipStream_t stream) {
    const float* x    = (const float*)d_in[0];
    const float* h0   = (const float*)d_in[1];
    const float* W1   = (const float*)d_in[2];
    const float* W2   = (const float*)d_in[3];
    const float* Wgx  = (const float*)d_in[4];
    const float* Wgh  = (const float*)d_in[5];
    const float* bias = (const float*)d_in[6];
    float* out = (float*)d_out;
    float* ws  = (float*)d_ws;

    // Opt in to >64 KB dynamic LDS (needs 132,416 B; CU has 160 KB).
    hipFuncSetAttribute((const void*)elman_persistent,
                        hipFuncAttributeMaxDynamicSharedMemorySize, LDS_BYTES);

    void* args[] = {(void*)&x, (void*)&h0, (void*)&W1, (void*)&W2,
                    (void*)&Wgx, (void*)&Wgh, (void*)&bias,
                    (void*)&out, (void*)&ws};
    hipLaunchCooperativeKernel((const void*)elman_persistent,
                               dim3(NWG), dim3(TPB), args,
                               (unsigned)LDS_BYTES, stream);
}

// Round 2
// 26184.708 us; speedup vs baseline: 8.5053x; 8.5053x over previous
//
#include <hip/hip_runtime.h>

// Problem sizes (fixed by the reference)
constexpr int D_ = 1024, E_ = 2048, B_ = 16, T_ = 1024;
constexpr int NWG = 256, TPB = 512;
constexpr int R1 = 8;            // W1 rows per WG  (E/NWG)
constexpr int R2 = 4;            // W2/Wc/Wgx rows per WG (D/NWG)
constexpr int NK = 32;           // K-split factor (threads per (b) lane-group)
constexpr int ST_E = 68;         // LDS stride of a 64-float chunk (pad 4, 16B-aligned, bank-spread)
constexpr int ST_D = 36;         // LDS stride of a 32-float chunk
constexpr int ROW_E = NK * ST_E; // 2176 floats per 2048-wide row
constexpr int ROW_D = NK * ST_D; // 1152 floats per 1024-wide row

// LDS layout (floats)
constexpr int OFF_W1   = 0;                       // [R1][ROW_E]
constexpr int OFF_W2   = OFF_W1 + R1 * ROW_E;     // [R2][ROW_E]
constexpr int OFF_WC   = OFF_W2 + R2 * ROW_E;     // [R2][ROW_E]  Wcomb = Wgh@W2 slice
constexpr int OFF_WGX  = OFF_WC + R2 * ROW_E;     // [R2][ROW_D]
constexpr int OFF_RED  = OFF_WGX + R2 * ROW_D;    // [1024] reduction scratch
constexpr int OFF_BIAS = OFF_RED + 1024;          // [4]
constexpr int LDS_FLOATS = OFF_BIAS + 16;
constexpr int LDS_BYTES  = LDS_FLOATS * 4;        // 161,856 B
static_assert(LDS_BYTES <= 163840, "LDS over 160KB");

// ---- device-coherent (L1/L2-bypassing, IF$-backed) access helpers ----
__device__ __forceinline__ float ld_cg(const float* p) {
    return __hip_atomic_load(p, __ATOMIC_RELAXED, __HIP_MEMORY_SCOPE_AGENT);
}
__device__ __forceinline__ void st_cg(float* p, float v) {
    __hip_atomic_store(p, v, __ATOMIC_RELAXED, __HIP_MEMORY_SCOPE_AGENT);
}
__device__ __forceinline__ float2 ld_cg2(const float* p) {
    unsigned long long u = __hip_atomic_load((const unsigned long long*)p,
                                             __ATOMIC_RELAXED, __HIP_MEMORY_SCOPE_AGENT);
    float2 r; __builtin_memcpy(&r, &u, 8); return r;
}

// ---- lightweight grid barrier on a monotonic counter ----
// All communicated data uses sc-coherent ops, so no L2 writeback/invalidate is
// needed: visibility is guaranteed by vmcnt(0) (stores acked at coherence
// point) before the arrive-add, and coherent loads after the spin.
__device__ __forceinline__ void bar_arrive(unsigned* cnt) {
    asm volatile("s_waitcnt vmcnt(0)" ::: "memory");   // every thread drains its stores
    __syncthreads();                                   // all waves' stores are done
    if (threadIdx.x == 0)
        __hip_atomic_fetch_add(cnt, 1u, __ATOMIC_RELAXED, __HIP_MEMORY_SCOPE_AGENT);
}
__device__ __forceinline__ void bar_wait(unsigned* cnt, unsigned thr) {
    if (threadIdx.x == 0) {
        while (__hip_atomic_load(cnt, __ATOMIC_RELAXED, __HIP_MEMORY_SCOPE_AGENT) < thr)
            __builtin_amdgcn_s_sleep(1);
    }
    __syncthreads();
}

__device__ __forceinline__ float sum4(float4 v) { return (v.x + v.y) + (v.z + v.w); }

__global__ void __launch_bounds__(TPB, 1)
elman2(const float* __restrict__ x, const float* __restrict__ h0,
       const float* __restrict__ W1, const float* __restrict__ W2g,
       const float* __restrict__ Wgx, const float* __restrict__ Wgh,
       const float* __restrict__ bias, float* __restrict__ out,
       unsigned* __restrict__ cnt, float* __restrict__ hid /* [E][B] k-major */)
{
    extern __shared__ float lds[];
    const int g = blockIdx.x, tid = threadIdx.x;
    const int b = tid & 15, ks = tid >> 4;  // ks in [0,32)
    const int lane = tid & 63, wv_ = tid >> 6;

    // ================= prologue =================
    // (p1) stage this WG's 4 Wgh rows into scratch (temporarily in W1 area) + bias
    float* wghs = lds;  // [R2][1024] = 4096 floats, overwritten later by W1
    for (int i = tid; i < R2 * (D_ / 2); i += TPB) {
        int r = i >> 9, k2 = (i & 511) * 2;
        *(float2*)(wghs + r * D_ + k2) =
            *(const float2*)(Wgh + (size_t)(g * R2 + r) * D_ + k2);
    }
    if (tid < R2) lds[OFF_BIAS + tid] = bias[g * R2 + tid];
    __syncthreads();

    // (p2) Wcomb rows = Wgh_rows @ W2  -> chunked LDS (one-time, streams W2 8MB)
    {
        const int k0 = tid * 4;  // covers 2048
        float4 a0{0,0,0,0}, a1{0,0,0,0}, a2{0,0,0,0}, a3{0,0,0,0};
        const float* wp = W2g + k0;
        #pragma unroll 4
        for (int m = 0; m < D_; ++m) {
            float4 wv = *(const float4*)wp; wp += E_;
            float g0 = wghs[0*D_+m], g1 = wghs[1*D_+m], g2 = wghs[2*D_+m], g3 = wghs[3*D_+m];
            a0.x = fmaf(g0, wv.x, a0.x); a0.y = fmaf(g0, wv.y, a0.y);
            a0.z = fmaf(g0, wv.z, a0.z); a0.w = fmaf(g0, wv.w, a0.w);
            a1.x = fmaf(g1, wv.x, a1.x); a1.y = fmaf(g1, wv.y, a1.y);
            a1.z = fmaf(g1, wv.z, a1.z); a1.w = fmaf(g1, wv.w, a1.w);
            a2.x = fmaf(g2, wv.x, a2.x); a2.y = fmaf(g2, wv.y, a2.y);
            a2.z = fmaf(g2, wv.z, a2.z); a2.w = fmaf(g2, wv.w, a2.w);
            a3.x = fmaf(g3, wv.x, a3.x); a3.y = fmaf(g3, wv.y, a3.y);
            a3.z = fmaf(g3, wv.z, a3.z); a3.w = fmaf(g3, wv.w, a3.w);
        }
        const int c = k0 >> 6, o = k0 & 63;
        *(float4*)(lds + OFF_WC + 0*ROW_E + c*ST_E + o) = a0;
        *(float4*)(lds + OFF_WC + 1*ROW_E + c*ST_E + o) = a1;
        *(float4*)(lds + OFF_WC + 2*ROW_E + c*ST_E + o) = a2;
        *(float4*)(lds + OFF_WC + 3*ROW_E + c*ST_E + o) = a3;
    }
    __syncthreads();

    // (p3) stage W1, W2, Wgx slices into chunked LDS (overwrites wghs scratch)
    for (int i = tid; i < R1 * (E_ / 4); i += TPB) {
        int r = i >> 9, k = (i & 511) * 4;
        *(float4*)(lds + OFF_W1 + r*ROW_E + (k >> 6)*ST_E + (k & 63)) =
            *(const float4*)(W1 + (size_t)(g * R1 + r) * (2 * D_) + k);
    }
    for (int i = tid; i < R2 * (E_ / 4); i += TPB) {
        int r = i >> 9, k = (i & 511) * 4;
        *(float4*)(lds + OFF_W2 + r*ROW_E + (k >> 6)*ST_E + (k & 63)) =
            *(const float4*)(W2g + (size_t)(g * R2 + r) * E_ + k);
    }
    for (int i = tid; i < R2 * (D_ / 4); i += TPB) {
        int r = i >> 8, k = (i & 255) * 4;
        *(float4*)(lds + OFF_WGX + r*ROW_D + (k >> 5)*ST_D + (k & 31)) =
            *(const float4*)(Wgx + (size_t)(g * R2 + r) * D_ + k);
    }
    __syncthreads();

    // ================= recurrence =================
    unsigned wtgt = 0;
    for (int t = 0; t < T_; ++t) {
        const float* xt = x + (size_t)t * (B_ * D_);
        const float* hsrc = (t == 0) ? h0 : (out + (size_t)(t - 1) * (B_ * D_));

        // ---- P1 partials: thread ks owns 64-float chunk ks of the [x;h] concat
        float4 a1p[R1];
        #pragma unroll
        for (int r = 0; r < R1; ++r) a1p[r] = float4{0, 0, 0, 0};

        if (ks < 16) {  // x half — no dependency on previous step: overlap with wait
            const float* xp = xt + b * D_ + ks * 64;
            #pragma unroll 4
            for (int j = 0; j < 64; j += 4) {
                float4 av = *(const float4*)(xp + j);
                #pragma unroll
                for (int r = 0; r < R1; ++r) {
                    float4 wv = *(const float4*)(lds + OFF_W1 + r*ROW_E + ks*ST_E + j);
                    a1p[r].x = fmaf(av.x, wv.x, a1p[r].x);
                    a1p[r].y = fmaf(av.y, wv.y, a1p[r].y);
                    a1p[r].z = fmaf(av.z, wv.z, a1p[r].z);
                    a1p[r].w = fmaf(av.w, wv.w, a1p[r].w);
                }
            }
        }

        if (t) bar_wait(cnt, (wtgt += NWG));   // wait for out(t-1) from all WGs

        if (ks >= 16) {  // h half (coherent loads from d_out / h0)
            const float* hp = hsrc + b * D_ + (ks - 16) * 64;
            #pragma unroll 4
            for (int j = 0; j < 64; j += 4) {
                float2 p0 = ld_cg2(hp + j), p1 = ld_cg2(hp + j + 2);
                float4 av = {p0.x, p0.y, p1.x, p1.y};
                #pragma unroll
                for (int r = 0; r < R1; ++r) {
                    float4 wv = *(const float4*)(lds + OFF_W1 + r*ROW_E + ks*ST_E + j);
                    a1p[r].x = fmaf(av.x, wv.x, a1p[r].x);
                    a1p[r].y = fmaf(av.y, wv.y, a1p[r].y);
                    a1p[r].z = fmaf(av.z, wv.z, a1p[r].z);
                    a1p[r].w = fmaf(av.w, wv.w, a1p[r].w);
                }
            }
        }

        // reduce over ks: shfl within wave (4 ks groups), LDS across 8 waves
        {
            float s1[R1];
            #pragma unroll
            for (int r = 0; r < R1; ++r) {
                float v = sum4(a1p[r]);
                v += __shfl_xor(v, 16, 64);
                v += __shfl_xor(v, 32, 64);
                s1[r] = v;
            }
            if (lane < 16) {
                #pragma unroll
                for (int r = 0; r < R1; ++r)
                    lds[OFF_RED + r*128 + wv_*16 + b] = s1[r];
            }
            __syncthreads();
            if (tid < 128) {
                int r = tid >> 4, bb = tid & 15;
                float v = 0;
                #pragma unroll
                for (int w = 0; w < 8; ++w) v += lds[OFF_RED + r*128 + w*16 + bb];
                v = tanhf(v);
                st_cg(hid + (size_t)(g * R1 + r) * B_ + bb, v);  // [col][b]
            }
        }
        bar_arrive(cnt);   // hidden published

        // ---- overlap: gate x-part (Wgx @ x_t), no dependency on hidden
        float4 ux[R2];
        #pragma unroll
        for (int r = 0; r < R2; ++r) ux[r] = float4{0, 0, 0, 0};
        {
            const float* xp = xt + b * D_ + ks * 32;
            #pragma unroll 2
            for (int j = 0; j < 32; j += 4) {
                float4 av = *(const float4*)(xp + j);
                #pragma unroll
                for (int r = 0; r < R2; ++r) {
                    float4 wv = *(const float4*)(lds + OFF_WGX + r*ROW_D + ks*ST_D + j);
                    ux[r].x = fmaf(av.x, wv.x, ux[r].x);
                    ux[r].y = fmaf(av.y, wv.y, ux[r].y);
                    ux[r].z = fmaf(av.z, wv.z, ux[r].z);
                    ux[r].w = fmaf(av.w, wv.w, ux[r].w);
                }
            }
        }

        bar_wait(cnt, (wtgt += NWG));   // hidden ready from all WGs

        // ---- P2: hnew = W2@hidden, u += Wcomb@hidden; finalize out
        {
            float4 hn[R2], uu[R2];
            #pragma unroll
            for (int r = 0; r < R2; ++r) { hn[r] = float4{0,0,0,0}; uu[r] = float4{0,0,0,0}; }
            #pragma unroll 2
            for (int j = 0; j < 64; j += 4) {
                const int k = ks * 64 + j;
                float v0 = ld_cg(hid + (k + 0) * B_ + b);
                float v1 = ld_cg(hid + (k + 1) * B_ + b);
                float v2 = ld_cg(hid + (k + 2) * B_ + b);
                float v3 = ld_cg(hid + (k + 3) * B_ + b);
                #pragma unroll
                for (int r = 0; r < R2; ++r) {
                    float4 w2v = *(const float4*)(lds + OFF_W2 + r*ROW_E + ks*ST_E + j);
                    hn[r].x = fmaf(v0, w2v.x, hn[r].x);
                    hn[r].y = fmaf(v1, w2v.y, hn[r].y);
                    hn[r].z = fmaf(v2, w2v.z, hn[r].z);
                    hn[r].w = fmaf(v3, w2v.w, hn[r].w);
                    float4 wcv = *(const float4*)(lds + OFF_WC + r*ROW_E + ks*ST_E + j);
                    uu[r].x = fmaf(v0, wcv.x, uu[r].x);
                    uu[r].y = fmaf(v1, wcv.y, uu[r].y);
                    uu[r].z = fmaf(v2, wcv.z, uu[r].z);
                    uu[r].w = fmaf(v3, wcv.w, uu[r].w);
                }
            }
            float s2[2 * R2];
            #pragma unroll
            for (int r = 0; r < R2; ++r) {
                s2[r] = sum4(hn[r]);
                s2[R2 + r] = sum4(uu[r]) + sum4(ux[r]);
            }
            #pragma unroll
            for (int i = 0; i < 2 * R2; ++i) {
                float v = s2[i];
                v += __shfl_xor(v, 16, 64);
                v += __shfl_xor(v, 32, 64);
                s2[i] = v;
            }
            if (lane < 16) {
                #pragma unroll
                for (int i = 0; i < 2 * R2; ++i)
                    lds[OFF_RED + i*128 + wv_*16 + b] = s2[i];
            }
            __syncthreads();
            if (tid < 64) {
                int r = tid >> 4, bb = tid & 15;
                float hnv = 0, uv = 0;
                #pragma unroll
                for (int w = 0; w < 8; ++w) {
                    hnv += lds[OFF_RED + r*128 + w*16 + bb];
                    uv  += lds[OFF_RED + (R2 + r)*128 + w*16 + bb];
                }
                uv += lds[OFF_BIAS + r];
                float sig = 1.0f / (1.0f + __expf(-uv));
                st_cg(out + (size_t)t * (B_ * D_) + bb * D_ + (g * R2 + r),
                      hnv * (uv * sig));
            }
        }
        bar_arrive(cnt);   // out(t) published (next step's h)
    }
}

extern "C" void kernel_launch(void* const* d_in, const int* in_sizes, int n_in,
                              void* d_out, int out_size, void* d_ws, size_t ws_size,
                              hipStream_t stream) {
    const float* x    = (const float*)d_in[0];
    const float* h0   = (const float*)d_in[1];
    const float* W1   = (const float*)d_in[2];
    const float* W2   = (const float*)d_in[3];
    const float* Wgx  = (const float*)d_in[4];
    const float* Wgh  = (const float*)d_in[5];
    const float* bias = (const float*)d_in[6];
    float* out = (float*)d_out;

    unsigned* cnt = (unsigned*)d_ws;
    float* hid = (float*)((char*)d_ws + 256);   // [E][B] = 128 KB

    hipMemsetAsync(d_ws, 0, 256, stream);       // zero the barrier counter

    hipFuncSetAttribute((const void*)elman2,
                        hipFuncAttributeMaxDynamicSharedMemorySize, LDS_BYTES);

    void* args[] = {(void*)&x, (void*)&h0, (void*)&W1, (void*)&W2,
                    (void*)&Wgx, (void*)&Wgh, (void*)&bias,
                    (void*)&out, (void*)&cnt, (void*)&hid};
    hipLaunchCooperativeKernel((const void*)elman2,
                               dim3(NWG), dim3(TPB), args,
                               (unsigned)LDS_BYTES, stream);
}

// Round 3
// 18680.721 us; speedup vs baseline: 11.9218x; 1.4017x over previous
//
#include <hip/hip_runtime.h>

// Problem sizes (fixed by the reference)
constexpr int D_ = 1024, E_ = 2048, B_ = 16, T_ = 1024;
constexpr int NWG = 256, TPB = 512;
constexpr int R1 = 8;            // W1 rows per WG  (E/NWG)
constexpr int R2 = 4;            // W2/Wc/Wgx rows per WG (D/NWG)
constexpr int NK = 32;           // K-split factor
constexpr int ST_E = 68;         // LDS stride of a 64-float chunk
constexpr int ST_D = 36;         // LDS stride of a 32-float chunk
constexpr int ROW_E = NK * ST_E; // 2176 floats per 2048-wide row
constexpr int ROW_D = NK * ST_D; // 1152 floats per 1024-wide row

// LDS layout (floats)
constexpr int OFF_W1   = 0;                       // [R1][ROW_E]
constexpr int OFF_W2   = OFF_W1 + R1 * ROW_E;     // [R2][ROW_E]
constexpr int OFF_WC   = OFF_W2 + R2 * ROW_E;     // [R2][ROW_E]  Wcomb = Wgh@W2 slice
constexpr int OFF_WGX  = OFF_WC + R2 * ROW_E;     // [R2][ROW_D]
constexpr int OFF_RED  = OFF_WGX + R2 * ROW_D;    // [1024]
constexpr int OFF_BIAS = OFF_RED + 1024;          // [16]
constexpr int OFF_PK   = OFF_BIAS + 16;           // [256] pack scratch
constexpr int LDS_FLOATS = OFF_PK + 256;
constexpr int LDS_BYTES  = LDS_FLOATS * 4;        // 162,880 B
static_assert(LDS_BYTES <= 163840, "LDS over 160KB");

// ---- device-coherent (LLC-backed) helpers ----
__device__ __forceinline__ void stcg_u(unsigned* p, unsigned v) {
    __hip_atomic_store(p, v, __ATOMIC_RELAXED, __HIP_MEMORY_SCOPE_AGENT);
}
__device__ __forceinline__ uint2 ldcg_u2(const unsigned* p) {
    unsigned long long u = __hip_atomic_load((const unsigned long long*)p,
                                             __ATOMIC_RELAXED, __HIP_MEMORY_SCOPE_AGENT);
    uint2 r; __builtin_memcpy(&r, &u, 8); return r;
}

// ---- bf16 pack/unpack ----
__device__ __forceinline__ unsigned f2bf(float f) {
    unsigned u; __builtin_memcpy(&u, &f, 4);
    u += 0x7fffu + ((u >> 16) & 1u);   // RNE
    return u >> 16;
}
__device__ __forceinline__ unsigned packbf(float lo, float hi) {
    return f2bf(lo) | (f2bf(hi) << 16);
}
__device__ __forceinline__ float blo(unsigned u) {
    unsigned v = u << 16; float f; __builtin_memcpy(&f, &v, 4); return f;
}
__device__ __forceinline__ float bhi(unsigned u) {
    unsigned v = u & 0xffff0000u; float f; __builtin_memcpy(&f, &v, 4); return f;
}

// ---- sharded monotonic grid barrier (64 shards, 128B apart) ----
// Safety: sum >= 256*k first occurs only when every WG has arrived at
// barrier k (a WG cannot arrive at k+1 before passing wait(k), which
// itself requires sum >= 256*k) — same invariant as a single counter.
__device__ __forceinline__ void bar_arrive(unsigned* cnt, int g) {
    asm volatile("s_waitcnt vmcnt(0)" ::: "memory");   // all data stores acked
    __syncthreads();
    if (threadIdx.x == 0)
        __hip_atomic_fetch_add(cnt + (g & 63) * 32, 1u,
                               __ATOMIC_RELAXED, __HIP_MEMORY_SCOPE_AGENT);
}
__device__ __forceinline__ void bar_wait(unsigned* cnt, unsigned tgt) {
    if (threadIdx.x < 64) {
        const int lane = threadIdx.x;
        while (true) {
            unsigned v = __hip_atomic_load(cnt + lane * 32,
                                           __ATOMIC_RELAXED, __HIP_MEMORY_SCOPE_AGENT);
            #pragma unroll
            for (int o = 1; o < 64; o <<= 1) v += __shfl_xor(v, o, 64);
            if (v >= tgt) break;
            __builtin_amdgcn_s_sleep(2);
        }
    }
    __syncthreads();
}

__device__ __forceinline__ float sum4(float4 v) { return (v.x + v.y) + (v.z + v.w); }

#define FMA4(acc, av, wv) \
    acc.x = fmaf(av##0, wv.x, acc.x); acc.y = fmaf(av##1, wv.y, acc.y); \
    acc.z = fmaf(av##2, wv.z, acc.z); acc.w = fmaf(av##3, wv.w, acc.w);

__global__ void __launch_bounds__(TPB, 1)
elman3(const float* __restrict__ x, const float* __restrict__ h0,
       const float* __restrict__ W1, const float* __restrict__ W2g,
       const float* __restrict__ Wgx, const float* __restrict__ Wgh,
       const float* __restrict__ bias, float* __restrict__ out,
       unsigned* __restrict__ cnt,
       unsigned* __restrict__ hx   /* [B][D/2] bf16x2 carried h */,
       unsigned* __restrict__ hidx /* [B][E/2] bf16x2 hidden */)
{
    extern __shared__ float lds[];
    const int g = blockIdx.x, tid = threadIdx.x;
    const int b = tid & 15, ks = tid >> 4;        // ks in [0,32)
    const int lane = tid & 63, wv_ = tid >> 6;

    // ================= prologue =================
    float* wghs = lds;  // [R2][1024] scratch (overwritten later by W1)
    for (int i = tid; i < R2 * (D_ / 2); i += TPB) {
        int r = i >> 9, k2 = (i & 511) * 2;
        *(float2*)(wghs + r * D_ + k2) =
            *(const float2*)(Wgh + (size_t)(g * R2 + r) * D_ + k2);
    }
    if (tid < R2) lds[OFF_BIAS + tid] = bias[g * R2 + tid];
    __syncthreads();

    // Wcomb rows = Wgh_rows @ W2 (one-time)
    {
        const int k0 = tid * 4;
        float4 a0{0,0,0,0}, a1{0,0,0,0}, a2{0,0,0,0}, a3{0,0,0,0};
        const float* wp = W2g + k0;
        #pragma unroll 4
        for (int m = 0; m < D_; ++m) {
            float4 wv = *(const float4*)wp; wp += E_;
            float g0 = wghs[0*D_+m], g1 = wghs[1*D_+m], g2 = wghs[2*D_+m], g3 = wghs[3*D_+m];
            a0.x = fmaf(g0, wv.x, a0.x); a0.y = fmaf(g0, wv.y, a0.y);
            a0.z = fmaf(g0, wv.z, a0.z); a0.w = fmaf(g0, wv.w, a0.w);
            a1.x = fmaf(g1, wv.x, a1.x); a1.y = fmaf(g1, wv.y, a1.y);
            a1.z = fmaf(g1, wv.z, a1.z); a1.w = fmaf(g1, wv.w, a1.w);
            a2.x = fmaf(g2, wv.x, a2.x); a2.y = fmaf(g2, wv.y, a2.y);
            a2.z = fmaf(g2, wv.z, a2.z); a2.w = fmaf(g2, wv.w, a2.w);
            a3.x = fmaf(g3, wv.x, a3.x); a3.y = fmaf(g3, wv.y, a3.y);
            a3.z = fmaf(g3, wv.z, a3.z); a3.w = fmaf(g3, wv.w, a3.w);
        }
        const int c = k0 >> 6, o = k0 & 63;
        *(float4*)(lds + OFF_WC + 0*ROW_E + c*ST_E + o) = a0;
        *(float4*)(lds + OFF_WC + 1*ROW_E + c*ST_E + o) = a1;
        *(float4*)(lds + OFF_WC + 2*ROW_E + c*ST_E + o) = a2;
        *(float4*)(lds + OFF_WC + 3*ROW_E + c*ST_E + o) = a3;
    }
    __syncthreads();

    // stage W1, W2, Wgx slices (overwrites wghs scratch)
    for (int i = tid; i < R1 * (E_ / 4); i += TPB) {
        int r = i >> 9, k = (i & 511) * 4;
        *(float4*)(lds + OFF_W1 + r*ROW_E + (k >> 6)*ST_E + (k & 63)) =
            *(const float4*)(W1 + (size_t)(g * R1 + r) * (2 * D_) + k);
    }
    for (int i = tid; i < R2 * (E_ / 4); i += TPB) {
        int r = i >> 9, k = (i & 511) * 4;
        *(float4*)(lds + OFF_W2 + r*ROW_E + (k >> 6)*ST_E + (k & 63)) =
            *(const float4*)(W2g + (size_t)(g * R2 + r) * E_ + k);
    }
    for (int i = tid; i < R2 * (D_ / 4); i += TPB) {
        int r = i >> 8, k = (i & 255) * 4;
        *(float4*)(lds + OFF_WGX + r*ROW_D + (k >> 5)*ST_D + (k & 31)) =
            *(const float4*)(Wgx + (size_t)(g * R2 + r) * D_ + k);
    }
    __syncthreads();

    // ================= recurrence =================
    unsigned wtgt = 0;
    for (int t = 0; t < T_; ++t) {
        const float* xt = x + (size_t)t * (B_ * D_);

        float4 a1p[R1];
        #pragma unroll
        for (int r = 0; r < R1; ++r) a1p[r] = float4{0, 0, 0, 0};

        // ---- P1 x-part: cols ks*32..+31 (independent of t-1; overlaps waitA)
        {
            const float* xp = xt + b * D_ + ks * 32;
            const float* wb = lds + OFF_W1 + (ks >> 1) * ST_E + (ks & 1) * 32;
            #pragma unroll 4
            for (int j = 0; j < 32; j += 4) {
                float4 av = *(const float4*)(xp + j);
                float av0 = av.x, av1 = av.y, av2 = av.z, av3 = av.w;
                #pragma unroll
                for (int r = 0; r < R1; ++r) {
                    float4 wv = *(const float4*)(wb + r * ROW_E + j);
                    FMA4(a1p[r], av, wv);
                }
            }
        }

        if (t) bar_wait(cnt, (wtgt += NWG));   // h(t-1) ready

        // ---- P1 h-part: concat cols 1024 + ks*32..+31
        {
            const float* wb = lds + OFF_W1 + (16 + (ks >> 1)) * ST_E + (ks & 1) * 32;
            if (t == 0) {
                const float* hp = h0 + b * D_ + ks * 32;
                #pragma unroll 4
                for (int j = 0; j < 32; j += 4) {
                    float4 av = *(const float4*)(hp + j);
                    float av0 = av.x, av1 = av.y, av2 = av.z, av3 = av.w;
                    #pragma unroll
                    for (int r = 0; r < R1; ++r) {
                        float4 wv = *(const float4*)(wb + r * ROW_E + j);
                        FMA4(a1p[r], av, wv);
                    }
                }
            } else {
                const unsigned* hp = hx + b * (D_ / 2) + ks * 16;
                #pragma unroll 4
                for (int j = 0; j < 16; j += 2) {
                    uint2 u = ldcg_u2(hp + j);
                    float av0 = blo(u.x), av1 = bhi(u.x), av2 = blo(u.y), av3 = bhi(u.y);
                    #pragma unroll
                    for (int r = 0; r < R1; ++r) {
                        float4 wv = *(const float4*)(wb + r * ROW_E + 2 * j);
                        FMA4(a1p[r], av, wv);
                    }
                }
            }
        }

        // ---- reduce P1, tanh, publish hidden (bf16-packed)
        {
            float s1[R1];
            #pragma unroll
            for (int r = 0; r < R1; ++r) {
                float v = sum4(a1p[r]);
                v += __shfl_xor(v, 16, 64);
                v += __shfl_xor(v, 32, 64);
                s1[r] = v;
            }
            if (lane < 16) {
                #pragma unroll
                for (int r = 0; r < R1; ++r)
                    lds[OFF_RED + r * 128 + wv_ * 16 + b] = s1[r];
            }
            __syncthreads();
            if (tid < 128) {
                int r = tid >> 4, bb = tid & 15;
                float v = 0;
                #pragma unroll
                for (int w = 0; w < 8; ++w) v += lds[OFF_RED + r * 128 + w * 16 + bb];
                lds[OFF_PK + r * 16 + bb] = tanhf(v);
            }
            __syncthreads();
            if (tid < 64) {
                int r2 = tid >> 4, bb = tid & 15;
                unsigned u = packbf(lds[OFF_PK + (2 * r2) * 16 + bb],
                                    lds[OFF_PK + (2 * r2 + 1) * 16 + bb]);
                stcg_u(hidx + bb * (E_ / 2) + g * 4 + r2, u);
            }
        }
        bar_arrive(cnt, g);   // hidden published

        // ---- gate x-part (overlaps waitB)
        float4 ux[R2];
        #pragma unroll
        for (int r = 0; r < R2; ++r) ux[r] = float4{0, 0, 0, 0};
        {
            const float* xp = xt + b * D_ + ks * 32;
            #pragma unroll 2
            for (int j = 0; j < 32; j += 4) {
                float4 av = *(const float4*)(xp + j);
                float av0 = av.x, av1 = av.y, av2 = av.z, av3 = av.w;
                #pragma unroll
                for (int r = 0; r < R2; ++r) {
                    float4 wv = *(const float4*)(lds + OFF_WGX + r * ROW_D + ks * ST_D + j);
                    FMA4(ux[r], av, wv);
                }
            }
        }

        bar_wait(cnt, (wtgt += NWG));   // hidden ready

        // ---- P2: hnew = W2@hidden, u = Wcomb@hidden + gate-x; finalize
        {
            float4 hn[R2], uu[R2];
            #pragma unroll
            for (int r = 0; r < R2; ++r) { hn[r] = float4{0,0,0,0}; uu[r] = float4{0,0,0,0}; }
            const unsigned* hp = hidx + b * (E_ / 2) + ks * 32;
            #pragma unroll 4
            for (int j = 0; j < 32; j += 2) {
                uint2 u = ldcg_u2(hp + j);
                float av0 = blo(u.x), av1 = bhi(u.x), av2 = blo(u.y), av3 = bhi(u.y);
                #pragma unroll
                for (int r = 0; r < R2; ++r) {
                    float4 wA = *(const float4*)(lds + OFF_W2 + r * ROW_E + ks * ST_E + 2 * j);
                    FMA4(hn[r], av, wA);
                    float4 wC = *(const float4*)(lds + OFF_WC + r * ROW_E + ks * ST_E + 2 * j);
                    FMA4(uu[r], av, wC);
                }
            }
            float s2[2 * R2];
            #pragma unroll
            for (int r = 0; r < R2; ++r) {
                s2[r] = sum4(hn[r]);
                s2[R2 + r] = sum4(uu[r]) + sum4(ux[r]);
            }
            #pragma unroll
            for (int i = 0; i < 2 * R2; ++i) {
                float v = s2[i];
                v += __shfl_xor(v, 16, 64);
                v += __shfl_xor(v, 32, 64);
                s2[i] = v;
            }
            if (lane < 16) {
                #pragma unroll
                for (int i = 0; i < 2 * R2; ++i)
                    lds[OFF_RED + i * 128 + wv_ * 16 + b] = s2[i];
            }
            __syncthreads();
            if (tid < 64) {
                int r = tid >> 4, bb = tid & 15;
                float hnv = 0, uv = 0;
                #pragma unroll
                for (int w = 0; w < 8; ++w) {
                    hnv += lds[OFF_RED + r * 128 + w * 16 + bb];
                    uv  += lds[OFF_RED + (R2 + r) * 128 + w * 16 + bb];
                }
                uv += lds[OFF_BIAS + r];
                float sig = 1.0f / (1.0f + __expf(-uv));
                lds[OFF_PK + r * 16 + bb] = hnv * (uv * sig);
            }
            __syncthreads();
            if (tid < 32) {
                int r2 = tid >> 4, bb = tid & 15;   // r2 in [0,2)
                float lo = lds[OFF_PK + (2 * r2) * 16 + bb];
                float hi = lds[OFF_PK + (2 * r2 + 1) * 16 + bb];
                // out: plain cached store (never read by the kernel)
                *(float2*)(out + (size_t)t * (B_ * D_) + bb * D_ + g * 4 + 2 * r2) =
                    float2{lo, hi};
                // carried h: coherent bf16 pair
                stcg_u(hx + bb * (D_ / 2) + g * 2 + r2, packbf(lo, hi));
            }
        }
        bar_arrive(cnt, g);   // h(t) published
    }
}

extern "C" void kernel_launch(void* const* d_in, const int* in_sizes, int n_in,
                              void* d_out, int out_size, void* d_ws, size_t ws_size,
                              hipStream_t stream) {
    const float* x    = (const float*)d_in[0];
    const float* h0   = (const float*)d_in[1];
    const float* W1   = (const float*)d_in[2];
    const float* W2   = (const float*)d_in[3];
    const float* Wgx  = (const float*)d_in[4];
    const float* Wgh  = (const float*)d_in[5];
    const float* bias = (const float*)d_in[6];
    float* out = (float*)d_out;

    unsigned* cnt  = (unsigned*)d_ws;        // 64 shards * 32 uints = 8KB
    unsigned* hx   = cnt + 2048;             // [B][D/2] = 32KB
    unsigned* hidx = hx + B_ * (D_ / 2);     // [B][E/2] = 64KB

    hipMemsetAsync(d_ws, 0, 8192, stream);   // zero barrier shards (every launch)

    hipFuncSetAttribute((const void*)elman3,
                        hipFuncAttributeMaxDynamicSharedMemorySize, LDS_BYTES);

    void* args[] = {(void*)&x, (void*)&h0, (void*)&W1, (void*)&W2,
                    (void*)&Wgx, (void*)&Wgh, (void*)&bias,
                    (void*)&out, (void*)&cnt, (void*)&hx, (void*)&hidx};
    hipLaunchCooperativeKernel((const void*)elman3,
                               dim3(NWG), dim3(TPB), args,
                               (unsigned)LDS_BYTES, stream);
}

// Round 4
// 11472.089 us; speedup vs baseline: 19.4130x; 1.6284x over previous
//
#include <hip/hip_runtime.h>

// Problem sizes (fixed by the reference)
constexpr int D_ = 1024, E_ = 2048, B_ = 16, T_ = 1024;
constexpr int NWG = 128, TPB = 512;   // 128 WGs: 16 W1-rows, 8 W2/Wc/Wgx-rows each

typedef short bf16x8 __attribute__((ext_vector_type(8)));
typedef float f32x4  __attribute__((ext_vector_type(4)));

// ---- LDS byte offsets ----
constexpr int W1F   = 0;        // W1 frags:   64 kc * 1024 B = 64 KB
constexpr int W2CF  = 65536;    // [W2;Wc] frags: 64 kc * 1024 B = 64 KB
constexpr int WGXF  = 131072;   // Wgx compact frags: 32 kc * 512 B = 16 KB
constexpr int ZB    = 147456;   // 16 B zero block (gate cols 8..15)
constexpr int REDo  = 147472;   // 8 waves * 256 f32 = 8 KB
constexpr int GREDo = 155664;   // 8 waves * 128 f32 = 4 KB
constexpr int PKo   = 159760;   // 256 f32 pack scratch
constexpr int GPo   = 160784;   // 128 f32 gate-x partial (persists P1->P2)
constexpr int BIo   = 161296;   // 8 f32 bias slice
constexpr int LDS_BYTES = 161328;
static_assert(LDS_BYTES <= 163840, "LDS over 160KB");

// ---- device-coherent (LLC) helpers ----
__device__ __forceinline__ void stcg_u(unsigned* p, unsigned v) {
    __hip_atomic_store(p, v, __ATOMIC_RELAXED, __HIP_MEMORY_SCOPE_AGENT);
}
__device__ __forceinline__ uint2 ldcg_u2(const unsigned* p) {
    unsigned long long u = __hip_atomic_load((const unsigned long long*)p,
                                             __ATOMIC_RELAXED, __HIP_MEMORY_SCOPE_AGENT);
    uint2 r; __builtin_memcpy(&r, &u, 8); return r;
}

// ---- bf16 helpers ----
__device__ __forceinline__ unsigned f2bf(float f) {
    unsigned u; __builtin_memcpy(&u, &f, 4);
    u += 0x7fffu + ((u >> 16) & 1u);   // RNE
    return u >> 16;
}
__device__ __forceinline__ unsigned packbf(float lo, float hi) {
    return f2bf(lo) | (f2bf(hi) << 16);
}
__device__ __forceinline__ bf16x8 pack8(float4 a, float4 b) {
    union { unsigned short us[8]; bf16x8 v; } r;
    r.us[0] = (unsigned short)f2bf(a.x); r.us[1] = (unsigned short)f2bf(a.y);
    r.us[2] = (unsigned short)f2bf(a.z); r.us[3] = (unsigned short)f2bf(a.w);
    r.us[4] = (unsigned short)f2bf(b.x); r.us[5] = (unsigned short)f2bf(b.y);
    r.us[6] = (unsigned short)f2bf(b.z); r.us[7] = (unsigned short)f2bf(b.w);
    return r.v;
}
__device__ __forceinline__ bf16x8 frag_from(uint2 a, uint2 b) {
    union { unsigned u[4]; bf16x8 v; } r;
    r.u[0] = a.x; r.u[1] = a.y; r.u[2] = b.x; r.u[3] = b.y;
    return r.v;
}

// ---- sharded monotonic grid barrier (32 shards, 128 B apart) ----
__device__ __forceinline__ void bar_arrive(unsigned* cnt, int g) {
    asm volatile("s_waitcnt vmcnt(0)" ::: "memory");
    __syncthreads();
    if (threadIdx.x == 0)
        __hip_atomic_fetch_add(cnt + (g & 31) * 32, 1u,
                               __ATOMIC_RELAXED, __HIP_MEMORY_SCOPE_AGENT);
}
__device__ __forceinline__ void bar_wait(unsigned* cnt, unsigned tgt) {
    if (threadIdx.x < 32) {
        const int lane = threadIdx.x;
        while (true) {
            unsigned v = __hip_atomic_load(cnt + lane * 32,
                                           __ATOMIC_RELAXED, __HIP_MEMORY_SCOPE_AGENT);
            #pragma unroll
            for (int o = 1; o < 32; o <<= 1) v += __shfl_xor(v, o, 32);
            if (v >= tgt) break;
            __builtin_amdgcn_s_sleep(2);
        }
    }
    __syncthreads();
}

__global__ void __launch_bounds__(TPB, 1)
elman4(const float* __restrict__ x, const float* __restrict__ h0,
       const float* __restrict__ W1, const float* __restrict__ W2g,
       const float* __restrict__ Wgx, const float* __restrict__ Wgh,
       const float* __restrict__ bias, float* __restrict__ out,
       unsigned* __restrict__ cnt,
       unsigned* __restrict__ hx   /* [B][D/2] bf16x2, b-major carried h */,
       unsigned* __restrict__ hidx /* [B][E/2] bf16x2, b-major hidden */)
{
    extern __shared__ char sm[];
    float* REDF  = (float*)(sm + REDo);
    float* GREDF = (float*)(sm + GREDo);
    float* PKF   = (float*)(sm + PKo);
    float* GPF   = (float*)(sm + GPo);
    float* BIF   = (float*)(sm + BIo);

    const int g = blockIdx.x, tid = threadIdx.x;
    const int l = tid & 63, wv = tid >> 6;   // lane, wave
    const int c16 = l & 15, q = l >> 4;      // frag col / k-octet group

    // ================= prologue: build bf16 fragment LDS =================
    // (1) stage Wgh slice (8 rows f32) into W2CF region temporarily
    {
        float* wght = (float*)(sm + W2CF);
        for (int i = tid; i < 8 * D_; i += TPB)
            wght[i] = Wgh[(size_t)(g * 8 + (i >> 10)) * D_ + (i & 1023)];
        if (tid < 8) BIF[tid] = bias[g * 8 + tid];
        if (tid == 0) *(float4*)(sm + ZB) = float4{0, 0, 0, 0};
        __syncthreads();

        // (2) Wc = Wgh_slice @ W2  (f32, into W1F region)
        float* wcf = (float*)(sm + W1F);
        {
            const int k4 = tid * 4;
            float4 acc[8];
            #pragma unroll
            for (int r = 0; r < 8; ++r) acc[r] = float4{0, 0, 0, 0};
            const float* wp = W2g + k4;
            for (int m = 0; m < D_; ++m) {
                float4 wvv = *(const float4*)wp; wp += E_;
                #pragma unroll
                for (int r = 0; r < 8; ++r) {
                    float gm = wght[r * D_ + m];
                    acc[r].x = fmaf(gm, wvv.x, acc[r].x);
                    acc[r].y = fmaf(gm, wvv.y, acc[r].y);
                    acc[r].z = fmaf(gm, wvv.z, acc[r].z);
                    acc[r].w = fmaf(gm, wvv.w, acc[r].w);
                }
            }
            __syncthreads();   // wght fully consumed before overwriting W1F? (wcf != wght regions; sync for store order below)
            #pragma unroll
            for (int r = 0; r < 8; ++r) *(float4*)(wcf + r * E_ + k4) = acc[r];
        }
        __syncthreads();

        // (3) pack [W2;Wc] frags into W2CF (overwrites wght; reads wcf + global W2)
        for (int i = tid; i < 4096; i += TPB) {
            int kc = i >> 6, l2 = i & 63, cc = l2 & 15, qq = l2 >> 4;
            int k = kc * 32 + qq * 8;
            float4 lo, hi;
            if (cc < 8) {
                const float* src = W2g + (size_t)(g * 8 + cc) * E_ + k;
                lo = *(const float4*)src; hi = *(const float4*)(src + 4);
            } else {
                const float* src = wcf + (cc - 8) * E_ + k;
                lo = *(const float4*)src; hi = *(const float4*)(src + 4);
            }
            *(bf16x8*)(sm + W2CF + i * 16) = pack8(lo, hi);
        }
        __syncthreads();   // wcf consumed before W1F overwrite

        // (4) pack W1 frags into W1F (16 rows, K=2048)
        for (int i = tid; i < 4096; i += TPB) {
            int kc = i >> 6, l2 = i & 63, cc = l2 & 15, qq = l2 >> 4;
            const float* src = W1 + (size_t)(g * 16 + cc) * (2 * D_) + kc * 32 + qq * 8;
            *(bf16x8*)(sm + W1F + i * 16) =
                pack8(*(const float4*)src, *(const float4*)(src + 4));
        }
        // (5) pack Wgx compact frags (8 real cols only)
        for (int i = tid; i < 1024; i += TPB) {
            int kc = i >> 5, qq = (i >> 3) & 3, cc = i & 7;
            const float* src = Wgx + (size_t)(g * 8 + cc) * D_ + kc * 32 + qq * 8;
            *(bf16x8*)(sm + WGXF + kc * 512 + qq * 128 + cc * 16) =
                pack8(*(const float4*)src, *(const float4*)(src + 4));
        }
        __syncthreads();
    }

    // gate B-frag address (zero page for cols 8..15), reused every step
    const char* gz = sm + ZB;

    // ================= recurrence =================
    unsigned wtgt = 0;
    f32x4 accP1 = {0.f, 0.f, 0.f, 0.f}, accG = {0.f, 0.f, 0.f, 0.f};

    // x-work for t=0: 4 x-chunks -> 4 P1 mfma + 4 gate mfma
    {
        const float* xt = x;
        #pragma unroll
        for (int i = 0; i < 4; ++i) {
            int kc = wv + i * 8;                       // [0,32)
            const float* xp = xt + c16 * D_ + kc * 32 + q * 8;
            bf16x8 af = pack8(*(const float4*)xp, *(const float4*)(xp + 4));
            bf16x8 w1 = *(const bf16x8*)(sm + W1F + kc * 1024 + l * 16);
            accP1 = __builtin_amdgcn_mfma_f32_16x16x32_bf16(af, w1, accP1, 0, 0, 0);
            const char* ga = (c16 < 8) ? (sm + WGXF + kc * 512 + q * 128 + c16 * 16) : gz;
            bf16x8 wg = *(const bf16x8*)ga;
            accG = __builtin_amdgcn_mfma_f32_16x16x32_bf16(af, wg, accG, 0, 0, 0);
        }
    }

    for (int t = 0; t < T_; ++t) {
        if (t) bar_wait(cnt, (wtgt += NWG));   // h(t-1) ready

        // ---- P1 h-part: 4 h-chunks
        if (t == 0) {
            #pragma unroll
            for (int i = 0; i < 4; ++i) {
                int kc = 32 + wv + i * 8;
                const float* hp = h0 + c16 * D_ + (kc - 32) * 32 + q * 8;
                bf16x8 af = pack8(*(const float4*)hp, *(const float4*)(hp + 4));
                bf16x8 w1 = *(const bf16x8*)(sm + W1F + kc * 1024 + l * 16);
                accP1 = __builtin_amdgcn_mfma_f32_16x16x32_bf16(af, w1, accP1, 0, 0, 0);
            }
        } else {
            #pragma unroll
            for (int i = 0; i < 4; ++i) {
                int kc = 32 + wv + i * 8;
                const unsigned* hp = hx + c16 * (D_ / 2) + (kc - 32) * 16 + q * 4;
                bf16x8 af = frag_from(ldcg_u2(hp), ldcg_u2(hp + 2));
                bf16x8 w1 = *(const bf16x8*)(sm + W1F + kc * 1024 + l * 16);
                accP1 = __builtin_amdgcn_mfma_f32_16x16x32_bf16(af, w1, accP1, 0, 0, 0);
            }
        }

        // ---- reduce P1 + gate partials across waves
        #pragma unroll
        for (int i = 0; i < 4; ++i)
            REDF[wv * 256 + (q * 4 + i) * 16 + c16] = accP1[i];
        if (c16 < 8) {
            #pragma unroll
            for (int i = 0; i < 4; ++i)
                GREDF[wv * 128 + (q * 4 + i) * 8 + c16] = accG[i];
        }
        __syncthreads();
        if (tid < 256) {                 // hidden = tanh(sum)
            float s = 0;
            #pragma unroll
            for (int w = 0; w < 8; ++w) s += REDF[w * 256 + tid];
            PKF[tid] = tanhf(s);
        } else if (tid < 384) {          // gate-x partial
            int gt = tid - 256;
            float s = 0;
            #pragma unroll
            for (int w = 0; w < 8; ++w) s += GREDF[w * 128 + gt];
            GPF[gt] = s;
        }
        __syncthreads();
        if (tid < 128) {                 // publish hidden slice (bf16 pairs)
            int b = tid >> 3, rp = tid & 7;
            stcg_u(hidx + b * (E_ / 2) + g * 8 + rp,
                   packbf(PKF[b * 16 + 2 * rp], PKF[b * 16 + 2 * rp + 1]));
        }
        bar_arrive(cnt, g);   // hidden published

        // ---- x-work for t+1 (overlaps waitB)
        f32x4 accP1n = {0.f, 0.f, 0.f, 0.f}, accGn = {0.f, 0.f, 0.f, 0.f};
        if (t + 1 < T_) {
            const float* xt = x + (size_t)(t + 1) * (B_ * D_);
            #pragma unroll
            for (int i = 0; i < 4; ++i) {
                int kc = wv + i * 8;
                const float* xp = xt + c16 * D_ + kc * 32 + q * 8;
                bf16x8 af = pack8(*(const float4*)xp, *(const float4*)(xp + 4));
                bf16x8 w1 = *(const bf16x8*)(sm + W1F + kc * 1024 + l * 16);
                accP1n = __builtin_amdgcn_mfma_f32_16x16x32_bf16(af, w1, accP1n, 0, 0, 0);
                const char* ga = (c16 < 8) ? (sm + WGXF + kc * 512 + q * 128 + c16 * 16) : gz;
                bf16x8 wg = *(const bf16x8*)ga;
                accGn = __builtin_amdgcn_mfma_f32_16x16x32_bf16(af, wg, accGn, 0, 0, 0);
            }
        }

        bar_wait(cnt, (wtgt += NWG));   // hidden all ready

        // ---- P2: [hnew; u_c] = hidden @ [W2;Wc]^T  (8 chunks)
        f32x4 acc2 = {0.f, 0.f, 0.f, 0.f};
        #pragma unroll
        for (int i = 0; i < 8; ++i) {
            int kc = wv + i * 8;
            const unsigned* hp = hidx + c16 * (E_ / 2) + kc * 16 + q * 4;
            bf16x8 af = frag_from(ldcg_u2(hp), ldcg_u2(hp + 2));
            bf16x8 w2 = *(const bf16x8*)(sm + W2CF + kc * 1024 + l * 16);
            acc2 = __builtin_amdgcn_mfma_f32_16x16x32_bf16(af, w2, acc2, 0, 0, 0);
        }
        #pragma unroll
        for (int i = 0; i < 4; ++i)
            REDF[wv * 256 + (q * 4 + i) * 16 + c16] = acc2[i];
        __syncthreads();
        if (tid < 128) {                 // finalize out = hnew * silu(u)
            int b = tid >> 3, r = tid & 7;
            float hn = 0, uv = 0;
            #pragma unroll
            for (int w = 0; w < 8; ++w) {
                hn += REDF[w * 256 + b * 16 + r];
                uv += REDF[w * 256 + b * 16 + 8 + r];
            }
            uv += GPF[b * 8 + r] + BIF[r];
            float sig = 1.0f / (1.0f + __expf(-uv));
            float o = hn * (uv * sig);
            out[(size_t)t * (B_ * D_) + b * D_ + g * 8 + r] = o;   // plain cached
            PKF[b * 8 + r] = o;
        }
        __syncthreads();
        if (tid < 64) {                  // publish carried h (bf16 pairs)
            int b = tid >> 2, rp = tid & 3;
            stcg_u(hx + b * (D_ / 2) + g * 4 + rp,
                   packbf(PKF[b * 8 + 2 * rp], PKF[b * 8 + 2 * rp + 1]));
        }
        bar_arrive(cnt, g);   // h(t) published

        accP1 = accP1n; accG = accGn;
    }
}

extern "C" void kernel_launch(void* const* d_in, const int* in_sizes, int n_in,
                              void* d_out, int out_size, void* d_ws, size_t ws_size,
                              hipStream_t stream) {
    const float* x    = (const float*)d_in[0];
    const float* h0   = (const float*)d_in[1];
    const float* W1   = (const float*)d_in[2];
    const float* W2   = (const float*)d_in[3];
    const float* Wgx  = (const float*)d_in[4];
    const float* Wgh  = (const float*)d_in[5];
    const float* bias = (const float*)d_in[6];
    float* out = (float*)d_out;

    unsigned* cnt  = (unsigned*)d_ws;          // 32 shards * 32 uints = 4 KB
    unsigned* hx   = cnt + 1024;               // [B][D/2] = 32 KB
    unsigned* hidx = hx + B_ * (D_ / 2);       // [B][E/2] = 64 KB

    hipMemsetAsync(d_ws, 0, 4096, stream);     // zero barrier shards

    hipFuncSetAttribute((const void*)elman4,
                        hipFuncAttributeMaxDynamicSharedMemorySize, LDS_BYTES);

    void* args[] = {(void*)&x, (void*)&h0, (void*)&W1, (void*)&W2,
                    (void*)&Wgx, (void*)&Wgh, (void*)&bias,
                    (void*)&out, (void*)&cnt, (void*)&hx, (void*)&hidx};
    hipLaunchCooperativeKernel((const void*)elman4,
                               dim3(NWG), dim3(TPB), args,
                               (unsigned)LDS_BYTES, stream);
}